// Round 5
// baseline (125.652 us; speedup 1.0000x reference)
//
#include <hip/hip_runtime.h>

// min_m ||pred[b,n]-target[b,m]|| mean over (b,n). B=32, N=M=4096, fp32.
// fp32 VALU-bound (no fp32 MFMA on CDNA4). Floor: 3 FMA + 0.5 min3 per pair
// ~= 3.5 VALU lane-ops/pair -> ~27 us at ~2.1 GHz sustained.
//
// R4 lesson: LDS broadcast is NOT free — ds_read_b128 pays full 1024 B
// writeback (~12 cyc CU-wide), so 8 ds_read per 224-VALU tile loads the DS
// pipe to ~86% of the VALU pipe -> co-bottleneck, true VALU busy ~52%.
// R5: no LDS at all. Targets are wave-uniform -> scalar loads (s_load_dwordx16)
// from a pre-transformed float4 array in d_ws. Prep kernel also initializes
// wmin (drops the memset dispatch). P=4 preds/thread, MS=16 splits,
// 2048 blocks -> 8 blocks/CU, 32 waves/CU, zero LDS.

constexpr int Bc = 32;
constexpr int Nc = 4096;
constexpr int Mc = 4096;
constexpr int BLOCK = 256;
constexpr int P = 4;                    // preds per thread
constexpr int MS = 16;                  // target splits per batch
constexpr int TGTS = Mc / MS;           // 256 targets per split
constexpr int NCH = Nc / (BLOCK * P);   // 4 pred chunks per batch
// grid A = Bc * NCH * MS = 2048 blocks

// Transform targets to (-2tx,-2ty,-2tz,|t|^2) and init wmin to +inf bits.
// Bc*Mc == Bc*Nc == 131072, so one thread does one of each.
__global__ __launch_bounds__(BLOCK) void emd_prep_kernel(
    const float* __restrict__ target, float4* __restrict__ tf,
    unsigned int* __restrict__ wmin) {
  const int i = blockIdx.x * BLOCK + threadIdx.x;
  float tx = target[3 * i + 0];
  float ty = target[3 * i + 1];
  float tz = target[3 * i + 2];
  tf[i] = make_float4(-2.0f * tx, -2.0f * ty, -2.0f * tz,
                      fmaf(tx, tx, fmaf(ty, ty, tz * tz)));
  wmin[i] = 0xFFFFFFFFu;
}

__global__ __launch_bounds__(BLOCK, 8) void emd_partial_kernel(
    const float* __restrict__ pred, const float4* __restrict__ tf,
    unsigned int* __restrict__ wmin) {
  const int bid = blockIdx.x;
  const int b = bid >> 6;            // / (NCH*MS)
  const int chunk = (bid >> 4) & 3;  // NCH index
  const int ms = bid & 15;           // target-split index

  // Wave-uniform base into the transformed-target array -> scalar loads.
  const float4* tb = tf + (size_t)b * Mc + ms * TGTS;

  // P=4 pred points per thread, strided by BLOCK for coalesced loads.
  float px[P], py[P], pz[P];
  const int nbase = chunk * (BLOCK * P) + threadIdx.x;
#pragma unroll
  for (int k = 0; k < P; ++k) {
    const float* pb = pred + ((size_t)b * Nc + nbase + k * BLOCK) * 3;
    px[k] = pb[0]; py[k] = pb[1]; pz[k] = pb[2];
  }

  float r0[P], r1[P];
#pragma unroll
  for (int k = 0; k < P; ++k) { r0[k] = 3.4e38f; r1[k] = 3.4e38f; }

  // 8 uniform float4 loads per tile (-> 2x s_load_dwordx16), then
  // 32 pairs = 96 FMA + 16 min3 on the VALU. No LDS, no syncthreads.
#pragma unroll 2
  for (int m = 0; m < TGTS; m += 8) {
    float4 t0 = tb[m + 0];
    float4 t1 = tb[m + 1];
    float4 t2 = tb[m + 2];
    float4 t3 = tb[m + 3];
    float4 t4 = tb[m + 4];
    float4 t5 = tb[m + 5];
    float4 t6 = tb[m + 6];
    float4 t7 = tb[m + 7];
#pragma unroll
    for (int k = 0; k < P; ++k) {
      float d0 = fmaf(px[k], t0.x, fmaf(py[k], t0.y, fmaf(pz[k], t0.z, t0.w)));
      float d1 = fmaf(px[k], t1.x, fmaf(py[k], t1.y, fmaf(pz[k], t1.z, t1.w)));
      float d2 = fmaf(px[k], t2.x, fmaf(py[k], t2.y, fmaf(pz[k], t2.z, t2.w)));
      float d3 = fmaf(px[k], t3.x, fmaf(py[k], t3.y, fmaf(pz[k], t3.z, t3.w)));
      float d4 = fmaf(px[k], t4.x, fmaf(py[k], t4.y, fmaf(pz[k], t4.z, t4.w)));
      float d5 = fmaf(px[k], t5.x, fmaf(py[k], t5.y, fmaf(pz[k], t5.z, t5.w)));
      float d6 = fmaf(px[k], t6.x, fmaf(py[k], t6.y, fmaf(pz[k], t6.z, t6.w)));
      float d7 = fmaf(px[k], t7.x, fmaf(py[k], t7.y, fmaf(pz[k], t7.z, t7.w)));
      r0[k] = fminf(fminf(d0, d1), r0[k]);  // v_min3_f32
      r1[k] = fminf(fminf(d2, d3), r1[k]);
      r0[k] = fminf(fminf(d4, d5), r0[k]);
      r1[k] = fminf(fminf(d6, d7), r1[k]);
    }
  }

  // Cross-block min combine: d2 >= 0 (clamped), so float order == uint order.
#pragma unroll
  for (int k = 0; k < P; ++k) {
    float p2 = fmaf(px[k], px[k], fmaf(py[k], py[k], pz[k] * pz[k]));
    float d2 = fmaxf(fminf(r0[k], r1[k]) + p2, 0.0f);
    atomicMin(&wmin[b * Nc + nbase + k * BLOCK], __float_as_uint(d2));
  }
}

__global__ __launch_bounds__(1024) void emd_finish_kernel(
    const uint4* __restrict__ wmin, float* __restrict__ out) {
  __shared__ float wsum[16];
  float s0 = 0.0f, s1 = 0.0f, s2 = 0.0f, s3 = 0.0f;
#pragma unroll 4
  for (int i = threadIdx.x; i < Bc * Nc / 4; i += 1024) {
    uint4 v = wmin[i];
    s0 += sqrtf(__uint_as_float(v.x));
    s1 += sqrtf(__uint_as_float(v.y));
    s2 += sqrtf(__uint_as_float(v.z));
    s3 += sqrtf(__uint_as_float(v.w));
  }
  float s = (s0 + s1) + (s2 + s3);
#pragma unroll
  for (int off = 32; off > 0; off >>= 1) s += __shfl_down(s, off, 64);
  if ((threadIdx.x & 63) == 0) wsum[threadIdx.x >> 6] = s;
  __syncthreads();
  if (threadIdx.x == 0) {
    float tot = 0.0f;
#pragma unroll
    for (int w = 0; w < 16; ++w) tot += wsum[w];
    out[0] = tot * (1.0f / (float)(Bc * Nc));
  }
}

extern "C" void kernel_launch(void* const* d_in, const int* in_sizes, int n_in,
                              void* d_out, int out_size, void* d_ws, size_t ws_size,
                              hipStream_t stream) {
  const float* pred = (const float*)d_in[0];
  const float* target = (const float*)d_in[1];
  float* out = (float*)d_out;

  // ws layout: [wmin: Bc*Nc uints = 512 KB][tf: Bc*Mc float4 = 2 MB]
  unsigned int* wmin = (unsigned int*)d_ws;
  float4* tf = (float4*)((char*)d_ws + (size_t)Bc * Nc * sizeof(unsigned int));

  emd_prep_kernel<<<dim3(Bc * Mc / BLOCK), dim3(BLOCK), 0, stream>>>(target, tf, wmin);
  emd_partial_kernel<<<dim3(Bc * NCH * MS), dim3(BLOCK), 0, stream>>>(pred, tf, wmin);
  emd_finish_kernel<<<dim3(1), dim3(1024), 0, stream>>>((const uint4*)wmin, out);
}

// Round 6
// 100.272 us; speedup vs baseline: 1.2531x; 1.2531x over previous
//
#include <hip/hip_runtime.h>

// min_m ||pred[b,n]-target[b,m]|| mean over (b,n). B=32, N=M=4096, fp32.
// fp32 VALU-bound (no fp32 MFMA on CDNA4). Floor: 3 FMA + 0.5 min3 per pair
// = 3.5 VALU lane-ops/pair -> ~27 us at ~2.1 GHz sustained.
//
// R4 (46 us): LDS broadcast, P=8 -> DS pipe at ~86% of VALU pipe (8
// ds_read_b128 ~= 96 CU-cyc per 448 SIMD-cyc tile, x4 SIMDs sharing one DS
// pipe) -> co-bottleneck.  R5 (SMEM targets): 61 us — s_load drains
// lgkmcnt(0) per tile, scalar-cache thrash. SMEM is a latency path, not a
// streaming path. Reverted.
// R6: keep LDS, raise P to 16 -> DS share drops to ~43%, VALU is sole
// bottleneck. MS=32 splits (128 targets, 2 KB LDS), 1024 blocks. Single
// min-chain per pred keeps VGPR ~100 (4 waves/SIMD at launch_bounds(256,4)).

constexpr int Bc = 32;
constexpr int Nc = 4096;
constexpr int Mc = 4096;
constexpr int BLOCK = 256;
constexpr int P = 16;                   // preds per thread
constexpr int MS = 32;                  // target splits per batch
constexpr int TGTS = Mc / MS;           // 128 targets staged per block (2 KB)
// NCH = Nc/(BLOCK*P) = 1; grid A = Bc * MS = 1024 blocks -> 4 blocks/CU

__global__ __launch_bounds__(BLOCK) void emd_init_kernel(
    unsigned int* __restrict__ wmin, float* __restrict__ out) {
  const int i = blockIdx.x * BLOCK + threadIdx.x;
  wmin[i] = 0xFFFFFFFFu;  // +inf bits for unsigned atomicMin
  if (i == 0) out[0] = 0.0f;
}

__global__ __launch_bounds__(BLOCK, 4) void emd_partial_kernel(
    const float* __restrict__ pred, const float* __restrict__ target,
    unsigned int* __restrict__ wmin) {
  __shared__ float4 tgt[TGTS];  // 2 KB

  const int bid = blockIdx.x;
  const int b = bid >> 5;   // / MS
  const int ms = bid & 31;  // target-split index

  // Stage + transform 128 targets: (-2tx,-2ty,-2tz,|t|^2).
  if (threadIdx.x < TGTS) {
    const float* tb = target + ((size_t)b * Mc + ms * TGTS + threadIdx.x) * 3;
    float tx = tb[0], ty = tb[1], tz = tb[2];
    tgt[threadIdx.x] = make_float4(-2.0f * tx, -2.0f * ty, -2.0f * tz,
                                   fmaf(tx, tx, fmaf(ty, ty, tz * tz)));
  }
  __syncthreads();

  // P=16 pred points per thread, strided by BLOCK: covers all 4096 of batch b.
  float px[P], py[P], pz[P];
#pragma unroll
  for (int k = 0; k < P; ++k) {
    const float* pb = pred + ((size_t)b * Nc + threadIdx.x + k * BLOCK) * 3;
    px[k] = pb[0]; py[k] = pb[1]; pz[k] = pb[2];
  }

  float r[P];
#pragma unroll
  for (int k = 0; k < P; ++k) r[k] = 3.4e38f;

  // 4-target tile: 4 ds_read_b128 (~48 CU-cyc/wave) per 224 VALU wave-instr
  // (448 SIMD-cyc) -> DS pipe ~43% loaded with 4 SIMDs sharing it.
#pragma unroll 2
  for (int m = 0; m < TGTS; m += 4) {
    float4 t0 = tgt[m + 0];
    float4 t1 = tgt[m + 1];
    float4 t2 = tgt[m + 2];
    float4 t3 = tgt[m + 3];
#pragma unroll
    for (int k = 0; k < P; ++k) {
      float d0 = fmaf(px[k], t0.x, fmaf(py[k], t0.y, fmaf(pz[k], t0.z, t0.w)));
      float d1 = fmaf(px[k], t1.x, fmaf(py[k], t1.y, fmaf(pz[k], t1.z, t1.w)));
      float d2 = fmaf(px[k], t2.x, fmaf(py[k], t2.y, fmaf(pz[k], t2.z, t2.w)));
      float d3 = fmaf(px[k], t3.x, fmaf(py[k], t3.y, fmaf(pz[k], t3.z, t3.w)));
      r[k] = fminf(fminf(d0, d1), r[k]);  // v_min3_f32
      r[k] = fminf(fminf(d2, d3), r[k]);
    }
  }

  // Cross-block min combine: d2 >= 0 (clamped), so float order == uint order.
#pragma unroll
  for (int k = 0; k < P; ++k) {
    float p2 = fmaf(px[k], px[k], fmaf(py[k], py[k], pz[k] * pz[k]));
    float d2 = fmaxf(r[k] + p2, 0.0f);
    atomicMin(&wmin[b * Nc + threadIdx.x + k * BLOCK], __float_as_uint(d2));
  }
}

__global__ __launch_bounds__(BLOCK) void emd_finish_kernel(
    const uint4* __restrict__ wmin, float* __restrict__ out) {
  __shared__ float wsum[4];
  const int i = blockIdx.x * BLOCK + threadIdx.x;  // 32768 uint4 total
  uint4 v = wmin[i];
  float s = sqrtf(__uint_as_float(v.x)) + sqrtf(__uint_as_float(v.y)) +
            sqrtf(__uint_as_float(v.z)) + sqrtf(__uint_as_float(v.w));
#pragma unroll
  for (int off = 32; off > 0; off >>= 1) s += __shfl_down(s, off, 64);
  if ((threadIdx.x & 63) == 0) wsum[threadIdx.x >> 6] = s;
  __syncthreads();
  if (threadIdx.x == 0) {
    float tot = (wsum[0] + wsum[1]) + (wsum[2] + wsum[3]);
    atomicAdd(out, tot * (1.0f / (float)(Bc * Nc)));
  }
}

extern "C" void kernel_launch(void* const* d_in, const int* in_sizes, int n_in,
                              void* d_out, int out_size, void* d_ws, size_t ws_size,
                              hipStream_t stream) {
  const float* pred = (const float*)d_in[0];
  const float* target = (const float*)d_in[1];
  float* out = (float*)d_out;
  unsigned int* wmin = (unsigned int*)d_ws;  // Bc*Nc uints = 512 KB

  emd_init_kernel<<<dim3(Bc * Nc / BLOCK), dim3(BLOCK), 0, stream>>>(wmin, out);
  emd_partial_kernel<<<dim3(Bc * MS), dim3(BLOCK), 0, stream>>>(pred, target, wmin);
  emd_finish_kernel<<<dim3(Bc * Nc / 4 / BLOCK), dim3(BLOCK), 0, stream>>>(
      (const uint4*)wmin, out);
}